// Round 12
// baseline (566.663 us; speedup 1.0000x reference)
//
#include <hip/hip_runtime.h>
#include <hip/hip_bf16.h>
#include <math.h>

// ---------------------------------------------------------------------------
// SimpleBetterGCN, R12 = R11 + PACKED-ROW GATHERS.
// Measured invariant (R6/R9/R10/R11): ~26 cyc per wave-VMEM-instruction per
// CU, independent of payload (bf16 vs fp8) and MLP depth (4/8/16) => the spmm
// tier is bound by VMEM *instruction* processing, not bytes/lines/latency.
// Fix: one gather instruction fetches MULTIPLE rows via per-lane addresses
// (fp8 rows are small): spmm2att 4 rows/instr (16 lanes x uint2 per 128-B
// row), spmm1 8 rows/instr (8 lanes x uint2 per 64-B row). In-register
// redistribution via __shfl (bpermute, LDS pipe). Accumulator/curRow/flush
// stay WAVE-WIDE (R2/R5 trap was splitting state, not transport).
// ---------------------------------------------------------------------------

#define HID 128
#define NBA 1792         // spmm2att blocks
#define NW (NBA * 4)     // spmm2att chunks == waves
#define NBC 128          // att_cleanup blocks
#define NBT (NBA + NBC)  // total attention partials

using short8 = __attribute__((ext_vector_type(8))) short;
using floatx4 = __attribute__((ext_vector_type(4))) float;

__device__ __forceinline__ float relu(float v) { return v > 0.f ? v : 0.f; }

__device__ __forceinline__ unsigned short f2bf(float f) {
  unsigned u = __float_as_uint(f);
  u += 0x7FFFu + ((u >> 16) & 1u);
  return (unsigned short)(u >> 16);
}
__device__ __forceinline__ float bflo(unsigned u) {
  return __uint_as_float(u << 16);
}
__device__ __forceinline__ float bfhi(unsigned u) {
  return __uint_as_float(u & 0xFFFF0000u);
}
__device__ __forceinline__ float bfu(unsigned short u) {
  return __uint_as_float((unsigned)u << 16);
}

// --------------- prep: weight transpose+cast + x cast to fp8 ---------------
__global__ __launch_bounds__(256) void prep_kernel(
    const float* __restrict__ x, const float* __restrict__ fc1w,
    const float* __restrict__ fc2w, unsigned char* __restrict__ xb,
    unsigned short* __restrict__ w1t, unsigned short* __restrict__ w2t,
    int n4) {
  const int b = blockIdx.x;
  const int t = threadIdx.x;
  if (b < 32) {                       // w1t[n][k] = W1[k][n], 128x64 (bf16)
    int idx = b * 256 + t;
    int n = idx >> 6, k = idx & 63;
    w1t[idx] = f2bf(fc1w[k * 128 + n]);
  } else if (b < 96) {                // w2t[n][k] = W2[k][n], 128x128 (bf16)
    int idx = (b - 32) * 256 + t;
    int n = idx >> 7, k = idx & 127;
    w2t[idx] = f2bf(fc2w[k * 128 + n]);
  } else {                            // xb = fp8(x)
    int idx = (b - 96) * 256 + t;
    if (idx < n4) {
      float4 v = *(const float4*)&x[idx * 4];
      int w = __builtin_amdgcn_cvt_pk_fp8_f32(v.x, v.y, 0, false);
      w = __builtin_amdgcn_cvt_pk_fp8_f32(v.z, v.w, w, true);
      *(unsigned*)&xb[idx * 4] = (unsigned)w;
    }
  }
}

// --------------------------- SPMM1 (64-dim fp8, packed 8 rows/gather) ------
// ax[r,:] += v * xb[c,:]; rs[r] += v.  One uint2/lane: 8 lanes cover one
// 64-B row, so ONE gather instruction fetches 8 edges' rows.  Redistribute:
// lane l needs byte l of row q, held by lane (q<<3)|(l>>3), dword (l>>2)&1,
// byte (l&3).  Wave-wide accumulator + atomic flush (unchanged).
__global__ __launch_bounds__(256) void spmm1_kernel(
    const unsigned char* __restrict__ mat, const int* __restrict__ rows,
    const int* __restrict__ cols, const float* __restrict__ vals,
    float* __restrict__ ax, float* __restrict__ rs, int E) {
  int gw0 = (blockIdx.x * blockDim.x + threadIdx.x) >> 6;
  const int gw = __builtin_amdgcn_readfirstlane(gw0);
  const int lane = threadIdx.x & 63;
  const int nw = (gridDim.x * blockDim.x) >> 6;
  const int S = (E + nw - 1) / nw;
  int start = gw * S;
  int end = start + S;
  if (end > E) end = E;
  if (start >= end) return;

  const int qsel = lane >> 3;          // my load: edge q of the group
  const unsigned off = ((unsigned)lane & 7u) * 8u;
  const int srcb = lane >> 3;          // redistribution src base
  const bool selhi = (lane >> 2) & 1;  // u.y vs u.x
  const int sh8 = (lane & 3) * 8;      // byte shift

  float acc = 0.f, accv = 0.f;
  int curRow = rows[start];

  auto flush = [&]() {
    atomicAdd(ax + (size_t)curRow * 64 + lane, acc);
    if (lane == 0) atomicAdd(rs + curRow, accv);
    acc = 0.f;
    accv = 0.f;
  };

  auto proc8 = [&](uint2 u, int j, int c_, float v_, int r_) {
#pragma unroll
    for (int q = 0; q < 8; ++q) {
      int src = (q << 3) | srcb;
      unsigned ux = (unsigned)__shfl((int)u.x, src);
      unsigned uy = (unsigned)__shfl((int)u.y, src);
      unsigned d = (selhi ? uy : ux) >> sh8;
      float vq = __shfl(v_, j + q);
      int rq = __shfl(r_, j + q);
      if (rq != curRow) { flush(); curRow = rq; }
      acc = fmaf(vq, __builtin_amdgcn_cvt_f32_fp8((int)d, 0), acc);
      accv += vq;
    }
  };

  for (int base = start; base < end; base += 64) {
    const int cnt = min(64, end - base);
    int c_ = 0, r_ = 0;
    float v_ = 0.f;
    if (lane < cnt) {
      int e = base + lane;
      c_ = __builtin_nontemporal_load(&cols[e]);
      v_ = __builtin_nontemporal_load(&vals[e]);
      r_ = __builtin_nontemporal_load(&rows[e]);
    }

    int j = 0;
    // 16 edges per iter: two 8-row packed gathers in flight
    for (; j + 16 <= cnt; j += 16) {
      unsigned ca = (unsigned)__shfl(c_, j + qsel);
      unsigned cb = (unsigned)__shfl(c_, j + 8 + qsel);
      uint2 ua = *(const uint2*)(mat + (size_t)(ca * 64u + off));
      uint2 ub = *(const uint2*)(mat + (size_t)(cb * 64u + off));
      proc8(ua, j, c_, v_, r_);
      proc8(ub, j + 8, c_, v_, r_);
    }
    for (; j + 8 <= cnt; j += 8) {
      unsigned ca = (unsigned)__shfl(c_, j + qsel);
      uint2 ua = *(const uint2*)(mat + (size_t)(ca * 64u + off));
      proc8(ua, j, c_, v_, r_);
    }
    for (; j < cnt; ++j) {
      int c = __shfl(c_, j);
      float v = __shfl(v_, j);
      int r = __shfl(r_, j);
      if (r != curRow) { flush(); curRow = r; }
      unsigned u = mat[(unsigned)c * 64u + (unsigned)lane];
      acc = fmaf(v, __builtin_amdgcn_cvt_f32_fp8((int)u, 0), acc);
      accv += v;
    }
  }
  flush();
}

// ------------------- fused FC (MFMA bf16): h1r(bf16) + t2(fp8) -------------
#define A1S 88
#define H1S 136
__global__ __launch_bounds__(256) void fc_fused_kernel(
    const float* __restrict__ ax, const float* __restrict__ rs,
    const unsigned short* __restrict__ w1t, const float* __restrict__ b1,
    const unsigned short* __restrict__ w2t, const float* __restrict__ b2,
    unsigned short* __restrict__ h1r, unsigned char* __restrict__ t2,
    int N) {
  __shared__ unsigned short a1[64 * A1S];
  __shared__ unsigned short h1[64 * H1S];
  __shared__ float rsl[64];
  const int t = threadIdx.x;
  const int R0 = blockIdx.x * 64;

  const int limit = N * 64;
#pragma unroll
  for (int i = 0; i < 4; ++i) {
    int f = t * 4 + i * 1024;
    int g = R0 * 64 + f;
    float4 v = {0.f, 0.f, 0.f, 0.f};
    if (g < limit) v = *(const float4*)&ax[g];
    int row = f >> 6, k = f & 63;
    ushort4 o;
    o.x = f2bf(v.x); o.y = f2bf(v.y); o.z = f2bf(v.z); o.w = f2bf(v.w);
    *(ushort4*)&a1[row * A1S + k] = o;
  }
  if (t < 64) rsl[t] = (R0 + t < N) ? rs[R0 + t] : 0.f;
  __syncthreads();

  const int w = t >> 6, lane = t & 63;
  const int quad = lane >> 4, ln = lane & 15;
  const int m0 = w * 16;

  floatx4 acc[8];
#pragma unroll
  for (int nt = 0; nt < 8; ++nt) acc[nt] = {0.f, 0.f, 0.f, 0.f};
#pragma unroll
  for (int k0 = 0; k0 < 64; k0 += 32) {
    short8 af = *(short8*)&a1[(m0 + ln) * A1S + k0 + quad * 8];
#pragma unroll
    for (int nt = 0; nt < 8; ++nt) {
      short8 bf = *(const short8*)&w1t[(nt * 16 + ln) * 64 + k0 + quad * 8];
      acc[nt] = __builtin_amdgcn_mfma_f32_16x16x32_bf16(af, bf, acc[nt], 0, 0, 0);
    }
  }
  floatx4 rsv = *(floatx4*)&rsl[m0 + quad * 4];
#pragma unroll
  for (int nt = 0; nt < 8; ++nt) {
    float b1v = b1[nt * 16 + ln];
#pragma unroll
    for (int r = 0; r < 4; ++r) {
      float v = relu(acc[nt][r] + rsv[r] * b1v);
      h1[(m0 + quad * 4 + r) * H1S + nt * 16 + ln] = f2bf(v);
    }
  }
  {
    int rloc = m0 + (lane >> 2);
    int gr = R0 + rloc;
    int cq = (lane & 3) * 32;
    if (gr < N) {
#pragma unroll
      for (int j = 0; j < 4; ++j) {
        ushort4 lo = *(ushort4*)&h1[rloc * H1S + cq + j * 8];
        ushort4 hi = *(ushort4*)&h1[rloc * H1S + cq + j * 8 + 4];
        *(ushort4*)&h1r[(size_t)gr * HID + cq + j * 8] = lo;
        *(ushort4*)&h1r[(size_t)gr * HID + cq + j * 8 + 4] = hi;
      }
    }
  }

  floatx4 acc2[8];
#pragma unroll
  for (int nt = 0; nt < 8; ++nt) acc2[nt] = {0.f, 0.f, 0.f, 0.f};
#pragma unroll
  for (int k0 = 0; k0 < 128; k0 += 32) {
    short8 af = *(short8*)&h1[(m0 + ln) * H1S + k0 + quad * 8];
#pragma unroll
    for (int nt = 0; nt < 8; ++nt) {
      short8 bf = *(const short8*)&w2t[(nt * 16 + ln) * 128 + k0 + quad * 8];
      acc2[nt] = __builtin_amdgcn_mfma_f32_16x16x32_bf16(af, bf, acc2[nt], 0, 0, 0);
    }
  }
#pragma unroll
  for (int nt = 0; nt < 8; ++nt) {
    float b2v = b2[nt * 16 + ln];
#pragma unroll
    for (int r = 0; r < 4; ++r) {
      h1[(m0 + quad * 4 + r) * H1S + nt * 16 + ln] = f2bf(acc2[nt][r] + b2v);
    }
  }
  {
    int rloc = m0 + (lane >> 2);
    int gr = R0 + rloc;
    int cq = (lane & 3) * 32;
    if (gr < N) {
#pragma unroll
      for (int j = 0; j < 4; ++j) {
        ushort4 lo = *(ushort4*)&h1[rloc * H1S + cq + j * 8];
        ushort4 hi = *(ushort4*)&h1[rloc * H1S + cq + j * 8 + 4];
        int w0 = __builtin_amdgcn_cvt_pk_fp8_f32(bfu(lo.x), bfu(lo.y), 0, false);
        w0 = __builtin_amdgcn_cvt_pk_fp8_f32(bfu(lo.z), bfu(lo.w), w0, true);
        int w1 = __builtin_amdgcn_cvt_pk_fp8_f32(bfu(hi.x), bfu(hi.y), 0, false);
        w1 = __builtin_amdgcn_cvt_pk_fp8_f32(bfu(hi.z), bfu(hi.w), w1, true);
        uint2 o;
        o.x = (unsigned)w0;
        o.y = (unsigned)w1;
        *(uint2*)&t2[(size_t)gr * HID + cq + j * 8] = o;
      }
    }
  }
}

// --------------------------- SPMM2 + fused attention (4 rows/gather) -------
// One uint2/lane: 16 lanes cover one 128-B fp8 row -> ONE gather instruction
// fetches 4 edges' rows.  Redistribute: lane l needs bytes 2l,2l+1 of row q,
// held by lane (q<<4)|(l>>2), dword (l>>1)&1, ushort (l&1).
__global__ __launch_bounds__(256) void spmm2att_kernel(
    const unsigned char* __restrict__ mat, const unsigned short* __restrict__ h1r,
    const int* __restrict__ rows, const int* __restrict__ cols,
    const float* __restrict__ vals, const float* __restrict__ attw,
    const float* __restrict__ attb,
    int* __restrict__ rowF, int* __restrict__ rowL,
    float* __restrict__ dataF, float* __restrict__ dataL,
    float* __restrict__ pm, float* __restrict__ pden, float* __restrict__ pnum,
    int E, int S) {
  __shared__ float sm[4], sden[4], snum[4][HID];
  const int w = threadIdx.x >> 6;
  const int lane = threadIdx.x & 63;
  int ch0 = blockIdx.x * 4 + w;
  const int chunk = __builtin_amdgcn_readfirstlane(ch0);
  const int start = chunk * S;
  const int end = min(start + S, E);
  const int d2 = lane * 2;
  const float2 wv = *(const float2*)(attw + d2);
  const float battn = attb[0];

  const int qsel = lane >> 4;            // my load: edge q of the group
  const unsigned off = ((unsigned)lane & 15u) * 8u;
  const int srcb = lane >> 2;            // redistribution src base
  const bool selhi = (lane >> 1) & 1;    // u.y vs u.x
  const int sh16 = (lane & 1) * 16;      // ushort shift

  float m = -INFINITY, den = 0.f, nx = 0.f, ny = 0.f;
  int fRow = -1, lRow = -1;

  if (start < end) {
    const int firstRow = rows[start];
    const bool cont = (start > 0) && (rows[start - 1] == firstRow);
    float2 acc = {0.f, 0.f};
    int curRow = firstRow;

    auto attproc = [&](int r, float2 a) {
      unsigned hu = *(const unsigned*)&h1r[(size_t)r * HID + d2];
      float hx = bflo(hu) + relu(a.x);
      float hy = bfhi(hu) + relu(a.y);
      float p = hx * wv.x + hy * wv.y;
#pragma unroll
      for (int off2 = 1; off2 < 64; off2 <<= 1) p += __shfl_xor(p, off2);
      float sc = p + battn;
      if (sc > m) {
        float s = expf(m - sc);  // first row: exp(-inf)=0
        den *= s; nx *= s; ny *= s;
        m = sc;
      }
      float e = expf(sc - m);
      den += e;
      nx = fmaf(e, hx, nx);
      ny = fmaf(e, hy, ny);
    };
    auto emit = [&](int nextRow) {
      if (curRow == firstRow && cont) {
        *(float2*)&dataF[(size_t)chunk * HID + d2] = acc;
        fRow = curRow;
      } else {
        attproc(curRow, acc);
      }
      acc.x = acc.y = 0.f;
      curRow = nextRow;
    };

    auto proc4 = [&](uint2 u, int j, float v_, int r_) {
#pragma unroll
      for (int q = 0; q < 4; ++q) {
        int src = (q << 4) | srcb;
        unsigned ux = (unsigned)__shfl((int)u.x, src);
        unsigned uy = (unsigned)__shfl((int)u.y, src);
        unsigned d = (selhi ? uy : ux) >> sh16;
        float vq = __shfl(v_, j + q);
        int rq = __shfl(r_, j + q);
        if (rq != curRow) emit(rq);
        acc.x = fmaf(vq, __builtin_amdgcn_cvt_f32_fp8((int)d, 0), acc.x);
        acc.y = fmaf(vq, __builtin_amdgcn_cvt_f32_fp8((int)d, 1), acc.y);
      }
    };

    for (int base = start; base < end; base += 64) {
      const int cnt = min(64, end - base);
      int c_ = 0, r_ = 0;
      float v_ = 0.f;
      if (lane < cnt) {
        int e = base + lane;
        c_ = __builtin_nontemporal_load(&cols[e]);
        v_ = __builtin_nontemporal_load(&vals[e]);
        r_ = __builtin_nontemporal_load(&rows[e]);
      }
      int j = 0;
      // 8 edges per iter: two 4-row packed gathers in flight
      for (; j + 8 <= cnt; j += 8) {
        unsigned ca = (unsigned)__shfl(c_, j + qsel);
        unsigned cb = (unsigned)__shfl(c_, j + 4 + qsel);
        uint2 ua = *(const uint2*)(mat + (size_t)(ca * 128u + off));
        uint2 ub = *(const uint2*)(mat + (size_t)(cb * 128u + off));
        proc4(ua, j, v_, r_);
        proc4(ub, j + 4, v_, r_);
      }
      for (; j + 4 <= cnt; j += 4) {
        unsigned ca = (unsigned)__shfl(c_, j + qsel);
        uint2 ua = *(const uint2*)(mat + (size_t)(ca * 128u + off));
        proc4(ua, j, v_, r_);
      }
      for (; j < cnt; ++j) {
        int c = __shfl(c_, j);
        float v = __shfl(v_, j);
        int r = __shfl(r_, j);
        if (r != curRow) emit(r);
        unsigned u = *(const unsigned short*)(mat + (unsigned)c * 128u +
                                              (unsigned)d2);
        acc.x = fmaf(v, __builtin_amdgcn_cvt_f32_fp8((int)u, 0), acc.x);
        acc.y = fmaf(v, __builtin_amdgcn_cvt_f32_fp8((int)u, 1), acc.y);
      }
    }
    bool spanF = (end < E) && (rows[end] == curRow);
    if (curRow == firstRow && cont) {
      *(float2*)&dataF[(size_t)chunk * HID + d2] = acc;
      fRow = curRow;
    } else if (spanF) {
      *(float2*)&dataL[(size_t)chunk * HID + d2] = acc;
      lRow = curRow;
    } else {
      attproc(curRow, acc);
    }
  }
  if (lane == 0) { rowF[chunk] = fRow; rowL[chunk] = lRow; }

  if (lane == 0) { sm[w] = m; sden[w] = den; }
  snum[w][d2] = nx;
  snum[w][d2 + 1] = ny;
  __syncthreads();
  const int t = threadIdx.x;
  if (t < HID) {
    float M4 = fmaxf(fmaxf(sm[0], sm[1]), fmaxf(sm[2], sm[3]));
    float s0 = sden[0] > 0.f ? expf(sm[0] - M4) : 0.f;
    float s1 = sden[1] > 0.f ? expf(sm[1] - M4) : 0.f;
    float s2 = sden[2] > 0.f ? expf(sm[2] - M4) : 0.f;
    float s3 = sden[3] > 0.f ? expf(sm[3] - M4) : 0.f;
    pnum[(size_t)t * NBT + blockIdx.x] =
        snum[0][t] * s0 + snum[1][t] * s1 + snum[2][t] * s2 + snum[3][t] * s3;
    if (t == 0) {
      pden[blockIdx.x] = sden[0] * s0 + sden[1] * s1 + sden[2] * s2 + sden[3] * s3;
      pm[blockIdx.x] = M4;
    }
  }
}

// --------------------------- attention boundary cleanup --------------------
__global__ __launch_bounds__(256) void att_cleanup_kernel(
    const unsigned short* __restrict__ h1r,
    const int* __restrict__ rowF, const int* __restrict__ rowL,
    const float* __restrict__ dataF, const float* __restrict__ dataL,
    const float* __restrict__ attw, const float* __restrict__ attb,
    float* __restrict__ pm, float* __restrict__ pden, float* __restrict__ pnum) {
  __shared__ float sm[4], sden[4], snum[4][HID];
  const int w = threadIdx.x >> 6;
  const int lane = threadIdx.x & 63;
  int wv0 = blockIdx.x * 4 + w;
  const int gwv = __builtin_amdgcn_readfirstlane(wv0);
  const int nw = NBC * 4;
  const int d2 = lane * 2;
  const float2 wvv = *(const float2*)(attw + d2);
  const float battn = attb[0];

  float m = -INFINITY, den = 0.f, nx = 0.f, ny = 0.f;
  for (int c = gwv; c < NW; c += nw) {
    int r = rowL[c];
    if (r < 0) continue;
    float2 acc = *(const float2*)&dataL[(size_t)c * HID + d2];
    int c2 = c + 1;
    while (c2 < NW && rowF[c2] == r) {
      float2 a2 = *(const float2*)&dataF[(size_t)c2 * HID + d2];
      acc.x += a2.x; acc.y += a2.y;
      ++c2;
    }
    unsigned hu = *(const unsigned*)&h1r[(size_t)r * HID + d2];
    float hx = bflo(hu) + relu(acc.x);
    float hy = bfhi(hu) + relu(acc.y);
    float p = hx * wvv.x + hy * wvv.y;
#pragma unroll
    for (int off = 1; off < 64; off <<= 1) p += __shfl_xor(p, off);
    float sc = p + battn;
    if (sc > m) {
      float s = expf(m - sc);
      den *= s; nx *= s; ny *= s;
      m = sc;
    }
    float e = expf(sc - m);
    den += e;
    nx = fmaf(e, hx, nx);
    ny = fmaf(e, hy, ny);
  }

  if (lane == 0) { sm[w] = m; sden[w] = den; }
  snum[w][d2] = nx;
  snum[w][d2 + 1] = ny;
  __syncthreads();
  const int t = threadIdx.x;
  if (t < HID) {
    float M4 = fmaxf(fmaxf(sm[0], sm[1]), fmaxf(sm[2], sm[3]));
    float s0 = sden[0] > 0.f ? expf(sm[0] - M4) : 0.f;
    float s1 = sden[1] > 0.f ? expf(sm[1] - M4) : 0.f;
    float s2 = sden[2] > 0.f ? expf(sm[2] - M4) : 0.f;
    float s3 = sden[3] > 0.f ? expf(sm[3] - M4) : 0.f;
    int pb = NBA + blockIdx.x;
    pnum[(size_t)t * NBT + pb] =
        snum[0][t] * s0 + snum[1][t] * s1 + snum[2][t] * s2 + snum[3][t] * s3;
    if (t == 0) {
      pden[pb] = sden[0] * s0 + sden[1] * s1 + sden[2] * s2 + sden[3] * s3;
      pm[pb] = M4;
    }
  }
}

// --------------------------- combine partials + classifier -----------------
__global__ __launch_bounds__(1024) void att_combine_kernel(
    const float* __restrict__ pm, const float* __restrict__ pden,
    const float* __restrict__ pnum, const float* __restrict__ clsw,
    const float* __restrict__ clsb, float* __restrict__ out) {
  __shared__ float red[1024];
  __shared__ float scale[NBT];
  __shared__ float g[HID + 1];
  const int t = threadIdx.x;

  float mloc = -INFINITY;
  for (int i = t; i < NBT; i += 1024) mloc = fmaxf(mloc, pm[i]);
  red[t] = mloc;
  __syncthreads();
  for (int off = 512; off > 0; off >>= 1) {
    if (t < off) red[t] = fmaxf(red[t], red[t + off]);
    __syncthreads();
  }
  const float M = red[0];
  __syncthreads();

  float dloc = 0.f;
  for (int i = t; i < NBT; i += 1024) {
    float dv = pden[i];
    float sc = dv > 0.f ? expf(pm[i] - M) : 0.f;
    scale[i] = sc;
    dloc += dv * sc;
  }
  red[t] = dloc;
  __syncthreads();
  for (int off = 512; off > 0; off >>= 1) {
    if (t < off) red[t] += red[t + off];
    __syncthreads();
  }
  if (t == 0) g[HID] = red[0];
  __syncthreads();

  const int c = t >> 3, bb = t & 7;
  float acc = 0.f;
  for (int i = bb; i < NBT; i += 8) acc += pnum[(size_t)c * NBT + i] * scale[i];
  acc += __shfl_down(acc, 4);
  acc += __shfl_down(acc, 2);
  acc += __shfl_down(acc, 1);
  if (bb == 0) g[c] = acc;
  __syncthreads();

  if (t < 10) {
    float o = 0.f;
    for (int d = 0; d < HID; ++d) o = fmaf(g[d], clsw[d * 10 + t], o);
    out[t] = clsb[t] + o / g[HID];
  }
}

extern "C" void kernel_launch(void* const* d_in, const int* in_sizes, int n_in,
                              void* d_out, int out_size, void* d_ws,
                              size_t ws_size, hipStream_t stream) {
  const float* x = (const float*)d_in[0];
  const int* erows = (const int*)d_in[1];
  const int* ecols = (const int*)d_in[2];
  const float* evals = (const float*)d_in[3];
  const float* fc1w = (const float*)d_in[4];
  const float* fc1b = (const float*)d_in[5];
  const float* fc2w = (const float*)d_in[6];
  const float* fc2b = (const float*)d_in[7];
  const float* attw = (const float*)d_in[8];
  const float* attb = (const float*)d_in[9];
  const float* clsw = (const float*)d_in[10];
  const float* clsb = (const float*)d_in[11];
  float* out = (float*)d_out;

  const int N = in_sizes[0] / 64;   // 100000
  const int E = in_sizes[1];        // 3200000
  const int S = (E + NW - 1) / NW;

  char* p = (char*)d_ws;
  auto alloc = [&](size_t bytes) {
    char* q = p;
    p += (bytes + 255) & ~(size_t)255;
    return q;
  };
  unsigned char* xb = (unsigned char*)alloc((size_t)N * 64);     // fp8
  float* ax = (float*)alloc((size_t)N * 64 * 4);  // contiguous with rs
  float* rs = (float*)alloc((size_t)N * 4);
  unsigned short* h1r = (unsigned short*)alloc((size_t)N * HID * 2);
  unsigned char* t2 = (unsigned char*)alloc((size_t)N * HID);    // fp8
  unsigned short* w1t = (unsigned short*)alloc(128 * 64 * 2);
  unsigned short* w2t = (unsigned short*)alloc(128 * 128 * 2);
  int* rowF2 = (int*)alloc(NW * 4);
  int* rowL2 = (int*)alloc(NW * 4);
  float* dataF2 = (float*)alloc((size_t)NW * HID * 4);
  float* dataL2 = (float*)alloc((size_t)NW * HID * 4);
  float* pm = (float*)alloc(NBT * 4);
  float* pden = (float*)alloc(NBT * 4);
  float* pnum = (float*)alloc((size_t)HID * NBT * 4);

  const int n4 = N * 16;
  const int nblk = (N + 63) / 64;

  // Zero spmm1 accumulators (ax | rs contiguous, 26 MB)
  hipMemsetAsync(ax, 0, (size_t)N * 65 * 4, stream);

  prep_kernel<<<96 + (n4 + 255) / 256, 256, 0, stream>>>(x, fc1w, fc2w, xb,
                                                         w1t, w2t, n4);
  spmm1_kernel<<<2048, 256, 0, stream>>>(xb, erows, ecols, evals, ax, rs, E);
  fc_fused_kernel<<<nblk, 256, 0, stream>>>(ax, rs, w1t, fc1b, w2t, fc2b,
                                            h1r, t2, N);
  spmm2att_kernel<<<NBA, 256, 0, stream>>>(t2, h1r, erows, ecols, evals,
                                           attw, attb, rowF2, rowL2,
                                           dataF2, dataL2, pm, pden, pnum,
                                           E, S);
  att_cleanup_kernel<<<NBC, 256, 0, stream>>>(h1r, rowF2, rowL2, dataF2,
                                              dataL2, attw, attb, pm, pden,
                                              pnum);
  att_combine_kernel<<<1, 1024, 0, stream>>>(pm, pden, pnum, clsw, clsb, out);
}

// Round 13
// 439.624 us; speedup vs baseline: 1.2890x; 1.2890x over previous
//
#include <hip/hip_runtime.h>
#include <hip/hip_bf16.h>
#include <math.h>

// ---------------------------------------------------------------------------
// SimpleBetterGCN, R13 = R11 structure + SCALAR-PATH METADATA (no shfl).
// Cost-model fit across R10/R11/R12: per-edge cost = 2.4 cyc x VMEM_instr
// + ~8 cyc x shfl (ds_bpermute, per-CU LDS pipe). The 3 shfls/edge WERE the
// spmm floor (~125 us/CU). Fix: metadata indices are wave-uniform -> read
// cols[e]/vals[e]/rows[e] with uniform index, 8-edge unrolled => compiler
// emits s_load_dwordx8 to SGPRs (scalar cache; zero VALU/LDS-pipe cost).
// Gathers: per-lane, 1 VMEM/edge, 8 in flight (R12 packed transport
// reverted). Remaining floor = miss bytes (~184 MB @ ~2.9 TB/s ~= 63 us).
// ---------------------------------------------------------------------------

#define HID 128
#define NBA 1792         // spmm2att blocks
#define NW (NBA * 4)     // spmm2att chunks == waves
#define NBC 128          // att_cleanup blocks
#define NBT (NBA + NBC)  // total attention partials

using short8 = __attribute__((ext_vector_type(8))) short;
using floatx4 = __attribute__((ext_vector_type(4))) float;

__device__ __forceinline__ float relu(float v) { return v > 0.f ? v : 0.f; }

__device__ __forceinline__ unsigned short f2bf(float f) {
  unsigned u = __float_as_uint(f);
  u += 0x7FFFu + ((u >> 16) & 1u);
  return (unsigned short)(u >> 16);
}
__device__ __forceinline__ float bflo(unsigned u) {
  return __uint_as_float(u << 16);
}
__device__ __forceinline__ float bfhi(unsigned u) {
  return __uint_as_float(u & 0xFFFF0000u);
}
__device__ __forceinline__ float bfu(unsigned short u) {
  return __uint_as_float((unsigned)u << 16);
}

// --------------- prep: weight transpose+cast + x cast to fp8 ---------------
__global__ __launch_bounds__(256) void prep_kernel(
    const float* __restrict__ x, const float* __restrict__ fc1w,
    const float* __restrict__ fc2w, unsigned char* __restrict__ xb,
    unsigned short* __restrict__ w1t, unsigned short* __restrict__ w2t,
    int n4) {
  const int b = blockIdx.x;
  const int t = threadIdx.x;
  if (b < 32) {                       // w1t[n][k] = W1[k][n], 128x64 (bf16)
    int idx = b * 256 + t;
    int n = idx >> 6, k = idx & 63;
    w1t[idx] = f2bf(fc1w[k * 128 + n]);
  } else if (b < 96) {                // w2t[n][k] = W2[k][n], 128x128 (bf16)
    int idx = (b - 32) * 256 + t;
    int n = idx >> 7, k = idx & 127;
    w2t[idx] = f2bf(fc2w[k * 128 + n]);
  } else {                            // xb = fp8(x)
    int idx = (b - 96) * 256 + t;
    if (idx < n4) {
      float4 v = *(const float4*)&x[idx * 4];
      int w = __builtin_amdgcn_cvt_pk_fp8_f32(v.x, v.y, 0, false);
      w = __builtin_amdgcn_cvt_pk_fp8_f32(v.z, v.w, w, true);
      *(unsigned*)&xb[idx * 4] = (unsigned)w;
    }
  }
}

// --------------------------- SPMM1 (64-dim fp8, scalar metadata) -----------
// ax[r,:] += v * xb[c,:]; rs[r] += v.  One byte per lane (64-B row = 1 line).
// Metadata via uniform-index loads (s_load_dwordx8); 8 gathers in flight.
__global__ __launch_bounds__(256) void spmm1_kernel(
    const unsigned char* __restrict__ mat, const int* __restrict__ rows,
    const int* __restrict__ cols, const float* __restrict__ vals,
    float* __restrict__ ax, float* __restrict__ rs, int E) {
  int gw0 = (blockIdx.x * blockDim.x + threadIdx.x) >> 6;
  const int gw = __builtin_amdgcn_readfirstlane(gw0);
  const int lane = threadIdx.x & 63;
  const int nw = (gridDim.x * blockDim.x) >> 6;
  const int S = (E + nw - 1) / nw;
  int start = gw * S;
  int end = start + S;
  if (end > E) end = E;
  if (start >= end) return;

  float acc = 0.f, accv = 0.f;
  int curRow = rows[start];

  auto flush = [&]() {
    atomicAdd(ax + (size_t)curRow * 64 + lane, acc);
    if (lane == 0) atomicAdd(rs + curRow, accv);
    acc = 0.f;
    accv = 0.f;
  };

  int e = start;
  for (; e + 8 <= end; e += 8) {
    // uniform-index metadata (scalar loads)
    int c0 = cols[e + 0], c1 = cols[e + 1], c2 = cols[e + 2], c3 = cols[e + 3];
    int c4 = cols[e + 4], c5 = cols[e + 5], c6 = cols[e + 6], c7 = cols[e + 7];
    // 8 gathers in flight (saddr + lane offset)
    unsigned u0 = mat[(unsigned)c0 * 64u + (unsigned)lane];
    unsigned u1 = mat[(unsigned)c1 * 64u + (unsigned)lane];
    unsigned u2 = mat[(unsigned)c2 * 64u + (unsigned)lane];
    unsigned u3 = mat[(unsigned)c3 * 64u + (unsigned)lane];
    unsigned u4 = mat[(unsigned)c4 * 64u + (unsigned)lane];
    unsigned u5 = mat[(unsigned)c5 * 64u + (unsigned)lane];
    unsigned u6 = mat[(unsigned)c6 * 64u + (unsigned)lane];
    unsigned u7 = mat[(unsigned)c7 * 64u + (unsigned)lane];
    float v0 = vals[e + 0], v1 = vals[e + 1], v2 = vals[e + 2], v3 = vals[e + 3];
    float v4 = vals[e + 4], v5 = vals[e + 5], v6 = vals[e + 6], v7 = vals[e + 7];
    int r0 = rows[e + 0], r1 = rows[e + 1], r2 = rows[e + 2], r3 = rows[e + 3];
    int r4 = rows[e + 4], r5 = rows[e + 5], r6 = rows[e + 6], r7 = rows[e + 7];

    if (r0 != curRow) { flush(); curRow = r0; }
    acc = fmaf(v0, __builtin_amdgcn_cvt_f32_fp8((int)u0, 0), acc); accv += v0;
    if (r1 != curRow) { flush(); curRow = r1; }
    acc = fmaf(v1, __builtin_amdgcn_cvt_f32_fp8((int)u1, 0), acc); accv += v1;
    if (r2 != curRow) { flush(); curRow = r2; }
    acc = fmaf(v2, __builtin_amdgcn_cvt_f32_fp8((int)u2, 0), acc); accv += v2;
    if (r3 != curRow) { flush(); curRow = r3; }
    acc = fmaf(v3, __builtin_amdgcn_cvt_f32_fp8((int)u3, 0), acc); accv += v3;
    if (r4 != curRow) { flush(); curRow = r4; }
    acc = fmaf(v4, __builtin_amdgcn_cvt_f32_fp8((int)u4, 0), acc); accv += v4;
    if (r5 != curRow) { flush(); curRow = r5; }
    acc = fmaf(v5, __builtin_amdgcn_cvt_f32_fp8((int)u5, 0), acc); accv += v5;
    if (r6 != curRow) { flush(); curRow = r6; }
    acc = fmaf(v6, __builtin_amdgcn_cvt_f32_fp8((int)u6, 0), acc); accv += v6;
    if (r7 != curRow) { flush(); curRow = r7; }
    acc = fmaf(v7, __builtin_amdgcn_cvt_f32_fp8((int)u7, 0), acc); accv += v7;
  }
  for (; e < end; ++e) {
    int c = cols[e];
    float v = vals[e];
    int r = rows[e];
    if (r != curRow) { flush(); curRow = r; }
    unsigned u = mat[(unsigned)c * 64u + (unsigned)lane];
    acc = fmaf(v, __builtin_amdgcn_cvt_f32_fp8((int)u, 0), acc);
    accv += v;
  }
  flush();
}

// ------------------- fused FC (MFMA bf16): h1r(bf16) + t2(fp8) -------------
#define A1S 88
#define H1S 136
__global__ __launch_bounds__(256) void fc_fused_kernel(
    const float* __restrict__ ax, const float* __restrict__ rs,
    const unsigned short* __restrict__ w1t, const float* __restrict__ b1,
    const unsigned short* __restrict__ w2t, const float* __restrict__ b2,
    unsigned short* __restrict__ h1r, unsigned char* __restrict__ t2,
    int N) {
  __shared__ unsigned short a1[64 * A1S];
  __shared__ unsigned short h1[64 * H1S];
  __shared__ float rsl[64];
  const int t = threadIdx.x;
  const int R0 = blockIdx.x * 64;

  const int limit = N * 64;
#pragma unroll
  for (int i = 0; i < 4; ++i) {
    int f = t * 4 + i * 1024;
    int g = R0 * 64 + f;
    float4 v = {0.f, 0.f, 0.f, 0.f};
    if (g < limit) v = *(const float4*)&ax[g];
    int row = f >> 6, k = f & 63;
    ushort4 o;
    o.x = f2bf(v.x); o.y = f2bf(v.y); o.z = f2bf(v.z); o.w = f2bf(v.w);
    *(ushort4*)&a1[row * A1S + k] = o;
  }
  if (t < 64) rsl[t] = (R0 + t < N) ? rs[R0 + t] : 0.f;
  __syncthreads();

  const int w = t >> 6, lane = t & 63;
  const int quad = lane >> 4, ln = lane & 15;
  const int m0 = w * 16;

  floatx4 acc[8];
#pragma unroll
  for (int nt = 0; nt < 8; ++nt) acc[nt] = {0.f, 0.f, 0.f, 0.f};
#pragma unroll
  for (int k0 = 0; k0 < 64; k0 += 32) {
    short8 af = *(short8*)&a1[(m0 + ln) * A1S + k0 + quad * 8];
#pragma unroll
    for (int nt = 0; nt < 8; ++nt) {
      short8 bf = *(const short8*)&w1t[(nt * 16 + ln) * 64 + k0 + quad * 8];
      acc[nt] = __builtin_amdgcn_mfma_f32_16x16x32_bf16(af, bf, acc[nt], 0, 0, 0);
    }
  }
  floatx4 rsv = *(floatx4*)&rsl[m0 + quad * 4];
#pragma unroll
  for (int nt = 0; nt < 8; ++nt) {
    float b1v = b1[nt * 16 + ln];
#pragma unroll
    for (int r = 0; r < 4; ++r) {
      float v = relu(acc[nt][r] + rsv[r] * b1v);
      h1[(m0 + quad * 4 + r) * H1S + nt * 16 + ln] = f2bf(v);
    }
  }
  {
    int rloc = m0 + (lane >> 2);
    int gr = R0 + rloc;
    int cq = (lane & 3) * 32;
    if (gr < N) {
#pragma unroll
      for (int j = 0; j < 4; ++j) {
        ushort4 lo = *(ushort4*)&h1[rloc * H1S + cq + j * 8];
        ushort4 hi = *(ushort4*)&h1[rloc * H1S + cq + j * 8 + 4];
        *(ushort4*)&h1r[(size_t)gr * HID + cq + j * 8] = lo;
        *(ushort4*)&h1r[(size_t)gr * HID + cq + j * 8 + 4] = hi;
      }
    }
  }

  floatx4 acc2[8];
#pragma unroll
  for (int nt = 0; nt < 8; ++nt) acc2[nt] = {0.f, 0.f, 0.f, 0.f};
#pragma unroll
  for (int k0 = 0; k0 < 128; k0 += 32) {
    short8 af = *(short8*)&h1[(m0 + ln) * H1S + k0 + quad * 8];
#pragma unroll
    for (int nt = 0; nt < 8; ++nt) {
      short8 bf = *(const short8*)&w2t[(nt * 16 + ln) * 128 + k0 + quad * 8];
      acc2[nt] = __builtin_amdgcn_mfma_f32_16x16x32_bf16(af, bf, acc2[nt], 0, 0, 0);
    }
  }
#pragma unroll
  for (int nt = 0; nt < 8; ++nt) {
    float b2v = b2[nt * 16 + ln];
#pragma unroll
    for (int r = 0; r < 4; ++r) {
      h1[(m0 + quad * 4 + r) * H1S + nt * 16 + ln] = f2bf(acc2[nt][r] + b2v);
    }
  }
  {
    int rloc = m0 + (lane >> 2);
    int gr = R0 + rloc;
    int cq = (lane & 3) * 32;
    if (gr < N) {
#pragma unroll
      for (int j = 0; j < 4; ++j) {
        ushort4 lo = *(ushort4*)&h1[rloc * H1S + cq + j * 8];
        ushort4 hi = *(ushort4*)&h1[rloc * H1S + cq + j * 8 + 4];
        int w0 = __builtin_amdgcn_cvt_pk_fp8_f32(bfu(lo.x), bfu(lo.y), 0, false);
        w0 = __builtin_amdgcn_cvt_pk_fp8_f32(bfu(lo.z), bfu(lo.w), w0, true);
        int w1 = __builtin_amdgcn_cvt_pk_fp8_f32(bfu(hi.x), bfu(hi.y), 0, false);
        w1 = __builtin_amdgcn_cvt_pk_fp8_f32(bfu(hi.z), bfu(hi.w), w1, true);
        uint2 o;
        o.x = (unsigned)w0;
        o.y = (unsigned)w1;
        *(uint2*)&t2[(size_t)gr * HID + cq + j * 8] = o;
      }
    }
  }
}

// --------------------------- SPMM2 + fused attention (scalar metadata) -----
__global__ __launch_bounds__(256) void spmm2att_kernel(
    const unsigned char* __restrict__ mat, const unsigned short* __restrict__ h1r,
    const int* __restrict__ rows, const int* __restrict__ cols,
    const float* __restrict__ vals, const float* __restrict__ attw,
    const float* __restrict__ attb,
    int* __restrict__ rowF, int* __restrict__ rowL,
    float* __restrict__ dataF, float* __restrict__ dataL,
    float* __restrict__ pm, float* __restrict__ pden, float* __restrict__ pnum,
    int E, int S) {
  __shared__ float sm[4], sden[4], snum[4][HID];
  const int w = threadIdx.x >> 6;
  const int lane = threadIdx.x & 63;
  int ch0 = blockIdx.x * 4 + w;
  const int chunk = __builtin_amdgcn_readfirstlane(ch0);
  const int start = chunk * S;
  const int end = min(start + S, E);
  const int d2 = lane * 2;
  const float2 wv = *(const float2*)(attw + d2);
  const float battn = attb[0];

  float m = -INFINITY, den = 0.f, nx = 0.f, ny = 0.f;
  int fRow = -1, lRow = -1;

  if (start < end) {
    const int firstRow = rows[start];
    const bool cont = (start > 0) && (rows[start - 1] == firstRow);
    float2 acc = {0.f, 0.f};
    int curRow = firstRow;

    auto attproc = [&](int r, float2 a) {
      unsigned hu = *(const unsigned*)&h1r[(size_t)r * HID + d2];
      float hx = bflo(hu) + relu(a.x);
      float hy = bfhi(hu) + relu(a.y);
      float p = hx * wv.x + hy * wv.y;
#pragma unroll
      for (int off2 = 1; off2 < 64; off2 <<= 1) p += __shfl_xor(p, off2);
      float sc = p + battn;
      if (sc > m) {
        float s = expf(m - sc);  // first row: exp(-inf)=0
        den *= s; nx *= s; ny *= s;
        m = sc;
      }
      float e = expf(sc - m);
      den += e;
      nx = fmaf(e, hx, nx);
      ny = fmaf(e, hy, ny);
    };
    auto emit = [&](int nextRow) {
      if (curRow == firstRow && cont) {
        *(float2*)&dataF[(size_t)chunk * HID + d2] = acc;
        fRow = curRow;
      } else {
        attproc(curRow, acc);
      }
      acc.x = acc.y = 0.f;
      curRow = nextRow;
    };

    int e = start;
    for (; e + 8 <= end; e += 8) {
      int c0 = cols[e + 0], c1 = cols[e + 1], c2 = cols[e + 2], c3 = cols[e + 3];
      int c4 = cols[e + 4], c5 = cols[e + 5], c6 = cols[e + 6], c7 = cols[e + 7];
      unsigned u0 = *(const unsigned short*)(mat + (unsigned)c0 * 128u + (unsigned)d2);
      unsigned u1 = *(const unsigned short*)(mat + (unsigned)c1 * 128u + (unsigned)d2);
      unsigned u2 = *(const unsigned short*)(mat + (unsigned)c2 * 128u + (unsigned)d2);
      unsigned u3 = *(const unsigned short*)(mat + (unsigned)c3 * 128u + (unsigned)d2);
      unsigned u4 = *(const unsigned short*)(mat + (unsigned)c4 * 128u + (unsigned)d2);
      unsigned u5 = *(const unsigned short*)(mat + (unsigned)c5 * 128u + (unsigned)d2);
      unsigned u6 = *(const unsigned short*)(mat + (unsigned)c6 * 128u + (unsigned)d2);
      unsigned u7 = *(const unsigned short*)(mat + (unsigned)c7 * 128u + (unsigned)d2);
      float v0 = vals[e + 0], v1 = vals[e + 1], v2 = vals[e + 2], v3 = vals[e + 3];
      float v4 = vals[e + 4], v5 = vals[e + 5], v6 = vals[e + 6], v7 = vals[e + 7];
      int r0 = rows[e + 0], r1 = rows[e + 1], r2 = rows[e + 2], r3 = rows[e + 3];
      int r4 = rows[e + 4], r5 = rows[e + 5], r6 = rows[e + 6], r7 = rows[e + 7];

      if (r0 != curRow) emit(r0);
      acc.x = fmaf(v0, __builtin_amdgcn_cvt_f32_fp8((int)u0, 0), acc.x);
      acc.y = fmaf(v0, __builtin_amdgcn_cvt_f32_fp8((int)u0, 1), acc.y);
      if (r1 != curRow) emit(r1);
      acc.x = fmaf(v1, __builtin_amdgcn_cvt_f32_fp8((int)u1, 0), acc.x);
      acc.y = fmaf(v1, __builtin_amdgcn_cvt_f32_fp8((int)u1, 1), acc.y);
      if (r2 != curRow) emit(r2);
      acc.x = fmaf(v2, __builtin_amdgcn_cvt_f32_fp8((int)u2, 0), acc.x);
      acc.y = fmaf(v2, __builtin_amdgcn_cvt_f32_fp8((int)u2, 1), acc.y);
      if (r3 != curRow) emit(r3);
      acc.x = fmaf(v3, __builtin_amdgcn_cvt_f32_fp8((int)u3, 0), acc.x);
      acc.y = fmaf(v3, __builtin_amdgcn_cvt_f32_fp8((int)u3, 1), acc.y);
      if (r4 != curRow) emit(r4);
      acc.x = fmaf(v4, __builtin_amdgcn_cvt_f32_fp8((int)u4, 0), acc.x);
      acc.y = fmaf(v4, __builtin_amdgcn_cvt_f32_fp8((int)u4, 1), acc.y);
      if (r5 != curRow) emit(r5);
      acc.x = fmaf(v5, __builtin_amdgcn_cvt_f32_fp8((int)u5, 0), acc.x);
      acc.y = fmaf(v5, __builtin_amdgcn_cvt_f32_fp8((int)u5, 1), acc.y);
      if (r6 != curRow) emit(r6);
      acc.x = fmaf(v6, __builtin_amdgcn_cvt_f32_fp8((int)u6, 0), acc.x);
      acc.y = fmaf(v6, __builtin_amdgcn_cvt_f32_fp8((int)u6, 1), acc.y);
      if (r7 != curRow) emit(r7);
      acc.x = fmaf(v7, __builtin_amdgcn_cvt_f32_fp8((int)u7, 0), acc.x);
      acc.y = fmaf(v7, __builtin_amdgcn_cvt_f32_fp8((int)u7, 1), acc.y);
    }
    for (; e < end; ++e) {
      int c = cols[e];
      float v = vals[e];
      int r = rows[e];
      if (r != curRow) emit(r);
      unsigned u = *(const unsigned short*)(mat + (unsigned)c * 128u + (unsigned)d2);
      acc.x = fmaf(v, __builtin_amdgcn_cvt_f32_fp8((int)u, 0), acc.x);
      acc.y = fmaf(v, __builtin_amdgcn_cvt_f32_fp8((int)u, 1), acc.y);
    }
    bool spanF = (end < E) && (rows[end] == curRow);
    if (curRow == firstRow && cont) {
      *(float2*)&dataF[(size_t)chunk * HID + d2] = acc;
      fRow = curRow;
    } else if (spanF) {
      *(float2*)&dataL[(size_t)chunk * HID + d2] = acc;
      lRow = curRow;
    } else {
      attproc(curRow, acc);
    }
  }
  if (lane == 0) { rowF[chunk] = fRow; rowL[chunk] = lRow; }

  if (lane == 0) { sm[w] = m; sden[w] = den; }
  snum[w][d2] = nx;
  snum[w][d2 + 1] = ny;
  __syncthreads();
  const int t = threadIdx.x;
  if (t < HID) {
    float M4 = fmaxf(fmaxf(sm[0], sm[1]), fmaxf(sm[2], sm[3]));
    float s0 = sden[0] > 0.f ? expf(sm[0] - M4) : 0.f;
    float s1 = sden[1] > 0.f ? expf(sm[1] - M4) : 0.f;
    float s2 = sden[2] > 0.f ? expf(sm[2] - M4) : 0.f;
    float s3 = sden[3] > 0.f ? expf(sm[3] - M4) : 0.f;
    pnum[(size_t)t * NBT + blockIdx.x] =
        snum[0][t] * s0 + snum[1][t] * s1 + snum[2][t] * s2 + snum[3][t] * s3;
    if (t == 0) {
      pden[blockIdx.x] = sden[0] * s0 + sden[1] * s1 + sden[2] * s2 + sden[3] * s3;
      pm[blockIdx.x] = M4;
    }
  }
}

// --------------------------- attention boundary cleanup --------------------
__global__ __launch_bounds__(256) void att_cleanup_kernel(
    const unsigned short* __restrict__ h1r,
    const int* __restrict__ rowF, const int* __restrict__ rowL,
    const float* __restrict__ dataF, const float* __restrict__ dataL,
    const float* __restrict__ attw, const float* __restrict__ attb,
    float* __restrict__ pm, float* __restrict__ pden, float* __restrict__ pnum) {
  __shared__ float sm[4], sden[4], snum[4][HID];
  const int w = threadIdx.x >> 6;
  const int lane = threadIdx.x & 63;
  int wv0 = blockIdx.x * 4 + w;
  const int gwv = __builtin_amdgcn_readfirstlane(wv0);
  const int nw = NBC * 4;
  const int d2 = lane * 2;
  const float2 wvv = *(const float2*)(attw + d2);
  const float battn = attb[0];

  float m = -INFINITY, den = 0.f, nx = 0.f, ny = 0.f;
  for (int c = gwv; c < NW; c += nw) {
    int r = rowL[c];
    if (r < 0) continue;
    float2 acc = *(const float2*)&dataL[(size_t)c * HID + d2];
    int c2 = c + 1;
    while (c2 < NW && rowF[c2] == r) {
      float2 a2 = *(const float2*)&dataF[(size_t)c2 * HID + d2];
      acc.x += a2.x; acc.y += a2.y;
      ++c2;
    }
    unsigned hu = *(const unsigned*)&h1r[(size_t)r * HID + d2];
    float hx = bflo(hu) + relu(acc.x);
    float hy = bfhi(hu) + relu(acc.y);
    float p = hx * wvv.x + hy * wvv.y;
#pragma unroll
    for (int off = 1; off < 64; off <<= 1) p += __shfl_xor(p, off);
    float sc = p + battn;
    if (sc > m) {
      float s = expf(m - sc);
      den *= s; nx *= s; ny *= s;
      m = sc;
    }
    float e = expf(sc - m);
    den += e;
    nx = fmaf(e, hx, nx);
    ny = fmaf(e, hy, ny);
  }

  if (lane == 0) { sm[w] = m; sden[w] = den; }
  snum[w][d2] = nx;
  snum[w][d2 + 1] = ny;
  __syncthreads();
  const int t = threadIdx.x;
  if (t < HID) {
    float M4 = fmaxf(fmaxf(sm[0], sm[1]), fmaxf(sm[2], sm[3]));
    float s0 = sden[0] > 0.f ? expf(sm[0] - M4) : 0.f;
    float s1 = sden[1] > 0.f ? expf(sm[1] - M4) : 0.f;
    float s2 = sden[2] > 0.f ? expf(sm[2] - M4) : 0.f;
    float s3 = sden[3] > 0.f ? expf(sm[3] - M4) : 0.f;
    int pb = NBA + blockIdx.x;
    pnum[(size_t)t * NBT + pb] =
        snum[0][t] * s0 + snum[1][t] * s1 + snum[2][t] * s2 + snum[3][t] * s3;
    if (t == 0) {
      pden[pb] = sden[0] * s0 + sden[1] * s1 + sden[2] * s2 + sden[3] * s3;
      pm[pb] = M4;
    }
  }
}

// --------------------------- combine partials + classifier -----------------
__global__ __launch_bounds__(1024) void att_combine_kernel(
    const float* __restrict__ pm, const float* __restrict__ pden,
    const float* __restrict__ pnum, const float* __restrict__ clsw,
    const float* __restrict__ clsb, float* __restrict__ out) {
  __shared__ float red[1024];
  __shared__ float scale[NBT];
  __shared__ float g[HID + 1];
  const int t = threadIdx.x;

  float mloc = -INFINITY;
  for (int i = t; i < NBT; i += 1024) mloc = fmaxf(mloc, pm[i]);
  red[t] = mloc;
  __syncthreads();
  for (int off = 512; off > 0; off >>= 1) {
    if (t < off) red[t] = fmaxf(red[t], red[t + off]);
    __syncthreads();
  }
  const float M = red[0];
  __syncthreads();

  float dloc = 0.f;
  for (int i = t; i < NBT; i += 1024) {
    float dv = pden[i];
    float sc = dv > 0.f ? expf(pm[i] - M) : 0.f;
    scale[i] = sc;
    dloc += dv * sc;
  }
  red[t] = dloc;
  __syncthreads();
  for (int off = 512; off > 0; off >>= 1) {
    if (t < off) red[t] += red[t + off];
    __syncthreads();
  }
  if (t == 0) g[HID] = red[0];
  __syncthreads();

  const int c = t >> 3, bb = t & 7;
  float acc = 0.f;
  for (int i = bb; i < NBT; i += 8) acc += pnum[(size_t)c * NBT + i] * scale[i];
  acc += __shfl_down(acc, 4);
  acc += __shfl_down(acc, 2);
  acc += __shfl_down(acc, 1);
  if (bb == 0) g[c] = acc;
  __syncthreads();

  if (t < 10) {
    float o = 0.f;
    for (int d = 0; d < HID; ++d) o = fmaf(g[d], clsw[d * 10 + t], o);
    out[t] = clsb[t] + o / g[HID];
  }
}

extern "C" void kernel_launch(void* const* d_in, const int* in_sizes, int n_in,
                              void* d_out, int out_size, void* d_ws,
                              size_t ws_size, hipStream_t stream) {
  const float* x = (const float*)d_in[0];
  const int* erows = (const int*)d_in[1];
  const int* ecols = (const int*)d_in[2];
  const float* evals = (const float*)d_in[3];
  const float* fc1w = (const float*)d_in[4];
  const float* fc1b = (const float*)d_in[5];
  const float* fc2w = (const float*)d_in[6];
  const float* fc2b = (const float*)d_in[7];
  const float* attw = (const float*)d_in[8];
  const float* attb = (const float*)d_in[9];
  const float* clsw = (const float*)d_in[10];
  const float* clsb = (const float*)d_in[11];
  float* out = (float*)d_out;

  const int N = in_sizes[0] / 64;   // 100000
  const int E = in_sizes[1];        // 3200000
  const int S = (E + NW - 1) / NW;

  char* p = (char*)d_ws;
  auto alloc = [&](size_t bytes) {
    char* q = p;
    p += (bytes + 255) & ~(size_t)255;
    return q;
  };
  unsigned char* xb = (unsigned char*)alloc((size_t)N * 64);     // fp8
  float* ax = (float*)alloc((size_t)N * 64 * 4);  // contiguous with rs
  float* rs = (float*)alloc((size_t)N * 4);
  unsigned short* h1r = (unsigned short*)alloc((size_t)N * HID * 2);
  unsigned char* t2 = (unsigned char*)alloc((size_t)N * HID);    // fp8
  unsigned short* w1t = (unsigned short*)alloc(128 * 64 * 2);
  unsigned short* w2t = (unsigned short*)alloc(128 * 128 * 2);
  int* rowF2 = (int*)alloc(NW * 4);
  int* rowL2 = (int*)alloc(NW * 4);
  float* dataF2 = (float*)alloc((size_t)NW * HID * 4);
  float* dataL2 = (float*)alloc((size_t)NW * HID * 4);
  float* pm = (float*)alloc(NBT * 4);
  float* pden = (float*)alloc(NBT * 4);
  float* pnum = (float*)alloc((size_t)HID * NBT * 4);

  const int n4 = N * 16;
  const int nblk = (N + 63) / 64;

  // Zero spmm1 accumulators (ax | rs contiguous, 26 MB)
  hipMemsetAsync(ax, 0, (size_t)N * 65 * 4, stream);

  prep_kernel<<<96 + (n4 + 255) / 256, 256, 0, stream>>>(x, fc1w, fc2w, xb,
                                                         w1t, w2t, n4);
  spmm1_kernel<<<2048, 256, 0, stream>>>(xb, erows, ecols, evals, ax, rs, E);
  fc_fused_kernel<<<nblk, 256, 0, stream>>>(ax, rs, w1t, fc1b, w2t, fc2b,
                                            h1r, t2, N);
  spmm2att_kernel<<<NBA, 256, 0, stream>>>(t2, h1r, erows, ecols, evals,
                                           attw, attb, rowF2, rowL2,
                                           dataF2, dataL2, pm, pden, pnum,
                                           E, S);
  att_cleanup_kernel<<<NBC, 256, 0, stream>>>(h1r, rowF2, rowL2, dataF2,
                                              dataL2, attw, attb, pm, pden,
                                              pnum);
  att_combine_kernel<<<1, 1024, 0, stream>>>(pm, pden, pnum, clsw, clsb, out);
}